// Round 4
// baseline (548.796 us; speedup 1.0000x reference)
//
#include <hip/hip_runtime.h>
#include <hip/hip_fp16.h>

// ---------------------------------------------------------------------------
// Heads: per-head QKV projections + causal attention, B=4 T=1024 C=1024 H=8.
// Round 4: 128x256 tile, BK=32, ring-3 LDS (72 KB) -> 2 blocks/CU, hoisted
// swizzled LDS offsets, XCD-aware block remap. 1 phase per K-tile:
// {8 ds_read | 3 global_load_lds -> bar -> 16 MFMA -> vmcnt(3) -> bar}.
// ---------------------------------------------------------------------------

typedef unsigned short u16;
typedef _Float16 f16x8 __attribute__((ext_vector_type(8)));
typedef float f32x4 __attribute__((ext_vector_type(4)));

__device__ __forceinline__ u16 f2h(float f) {
    union { __half h; u16 u; } cv;
    cv.h = __float2half(f);
    return cv.u;
}

__device__ __forceinline__ void gload_lds16(const u16* g, const u16* lds_base, unsigned off_bytes) {
    unsigned a32 = (unsigned)(uintptr_t)((const char*)lds_base + off_bytes);
    a32 = __builtin_amdgcn_readfirstlane(a32);
    __builtin_amdgcn_global_load_lds(
        (const __attribute__((address_space(1))) void*)(uintptr_t)g,
        (__attribute__((address_space(3))) void*)a32,
        16, 0, 0);
}

// ---------------------------------------------------------------------------
// gemm_v3: D[m,n] = scale * sum_k A[m,k] * Bt[n,k]   (operands [rows][K] fp16)
// tile 128(M) x 256(N), BK=32, 512 thr = 8 waves (2M x 4N), wave tile 64x64.
// LDS ring-3: A slots [128x32]=8KB @ {0,8K,16K}; B slots [256x32]=16KB
// @ 24K + {0,16K,32K}. Swizzle: byte ^= ((row>>1)&3)<<4 (both sides).
// OM: 0 = fp16 out, 2 = fp32 + causal tile skip, 3 = fp32 + causal K-limit.
// ---------------------------------------------------------------------------
template <int OM>
__global__ __launch_bounds__(512, 4) void gemm_v3(
    const u16* __restrict__ A, const u16* __restrict__ Bt, void* __restrict__ Cout,
    int lda, int ldb, int ldc,
    long sA_hi, long sA_lo, long sB_hi, long sB_lo, long sC_hi, long sC_lo,
    int K, float scale)
{
    // ---- XCD-aware remap (dispatch order: x fastest; XCD = linear id % 8) ----
    const int per_z = gridDim.x * gridDim.y;
    const int id = blockIdx.x + gridDim.x * (blockIdx.y + gridDim.y * blockIdx.z);
    const int z = id / per_z, iz = id - z * per_z;
    const int xcd = iz & 7, jj = iz >> 3;
    int tile_n, tile_m;
    if (per_z == 1024) {           // proj: 8x16 rect per XCD (A,B ~L2-fit)
        tile_n = (xcd >> 1) * 8 + (jj & 7);
        tile_m = (xcd & 1) * 16 + (jj >> 3);
    } else {                       // per_z==32: balanced tile_m row per XCD
        tile_n = jj;
        tile_m = (xcd + z) & 7;
    }
    if (OM == 2 && 2 * tile_n > tile_m) return;  // causal: no needed elements

    const int zh = z >> 3, zl = z & 7;
    const u16* Ab = A + (size_t)zh * sA_hi + (size_t)zl * sA_lo + (size_t)tile_m * 128 * lda;
    const u16* Bb = Bt + (size_t)zh * sB_hi + (size_t)zl * sB_lo + (size_t)tile_n * 256 * ldb;

    __shared__ __align__(16) u16 lds[36864];  // 72 KB
    const char* ldsc = (const char*)lds;

    const int t = threadIdx.x, w = t >> 6, l = t & 63;
    const int wm = w >> 2, wn = w & 3;       // wave tile: rows wm*64, cols wn*64
    const int frow = l & 15, fch = l >> 4;

    const int Kend = (OM == 3) ? min(K, tile_m * 128 + 128) : K;
    const int NT = Kend >> 5;                // >= 4, multiple of 4

    // staging: linear chunk -> (row, chunk^((row>>1)&3)) involution
    const int clin = w * 64 + l;
    const int srow = clin >> 2;
    const int sch = (clin & 3) ^ ((clin >> 3) & 3);
    const long eA = (long)srow * lda + sch * 8;
    const long eB = (long)srow * ldb + sch * 8;

    // hoisted per-lane swizzled read offsets (bytes)
    unsigned aO[4], bO[4];
#pragma unroll
    for (int i = 0; i < 4; ++i) {
        int row = wm * 64 + i * 16 + frow;
        aO[i] = (unsigned)((row * 64 + fch * 16) ^ (((row >> 1) & 3) << 4));
    }
#pragma unroll
    for (int i = 0; i < 4; ++i) {
        int row = wn * 64 + i * 16 + frow;
        bO[i] = (unsigned)(24576 + ((row * 64 + fch * 16) ^ (((row >> 1) & 3) << 4)));
    }

    f32x4 acc[4][4] = {};

#define STAGE(TILE, RB) do {                                                   \
        const u16* gA_ = Ab + eA + (size_t)(TILE) * 32;                        \
        gload_lds16(gA_, lds, (unsigned)((RB) * 8192 + w * 1024));             \
        const u16* gB_ = Bb + eB + (size_t)(TILE) * 32;                        \
        gload_lds16(gB_, lds, (unsigned)(24576 + (RB) * 16384 + w * 1024));    \
        gload_lds16(gB_ + (size_t)128 * ldb, lds,                              \
                    (unsigned)(24576 + (RB) * 16384 + 8192 + w * 1024));       \
    } while (0)

#define PH(TCUR, RB) do {                                                      \
        f16x8 af[4], bf[4];                                                    \
        _Pragma("unroll") for (int i2 = 0; i2 < 4; ++i2)                       \
            af[i2] = *(const f16x8*)(ldsc + (RB) * 8192 + aO[i2]);             \
        _Pragma("unroll") for (int i2 = 0; i2 < 4; ++i2)                       \
            bf[i2] = *(const f16x8*)(ldsc + (RB) * 16384 + bO[i2]);            \
        if ((TCUR) + 2 < NT) STAGE((TCUR) + 2, ((RB) + 2) % 3);                \
        asm volatile("s_barrier" ::: "memory");                                \
        __builtin_amdgcn_s_setprio(1);                                         \
        _Pragma("unroll") for (int mi = 0; mi < 4; ++mi)                       \
            _Pragma("unroll") for (int ni = 0; ni < 4; ++ni)                   \
                acc[mi][ni] = __builtin_amdgcn_mfma_f32_16x16x32_f16(          \
                    af[mi], bf[ni], acc[mi][ni], 0, 0, 0);                     \
        __builtin_amdgcn_s_setprio(0);                                         \
        if ((TCUR) < NT - 3) { asm volatile("s_waitcnt vmcnt(3)" ::: "memory"); } \
        else                 { asm volatile("s_waitcnt vmcnt(0)" ::: "memory"); } \
        asm volatile("s_barrier" ::: "memory");                                \
    } while (0)

    // prologue: tiles 0,1 -> slots 0,1; wait tile0 (keep tile1's 3 in flight)
    STAGE(0, 0);
    STAGE(1, 1);
    asm volatile("s_waitcnt vmcnt(3)" ::: "memory");
    asm volatile("s_barrier" ::: "memory");

    const int rem = NT % 3;
    const int tbEnd = NT - rem;
    for (int tb = 0; tb < tbEnd; tb += 3) {
        PH(tb + 0, 0);
        PH(tb + 1, 1);
        PH(tb + 2, 2);
    }
    if (rem >= 1) PH(tbEnd + 0, 0);
    if (rem == 2) PH(tbEnd + 1, 1);
#undef PH
#undef STAGE

    // epilogue: C/D layout col = l&15, row = (l>>4)*4 + r
    const int r0 = (l >> 4) * 4, cc = l & 15;
    const size_t cb_off = (size_t)zh * sC_hi + (size_t)zl * sC_lo;
#pragma unroll
    for (int mi = 0; mi < 4; ++mi) {
#pragma unroll
        for (int r = 0; r < 4; ++r) {
            size_t grow = (size_t)(tile_m * 128 + wm * 64 + mi * 16 + r0 + r);
#pragma unroll
            for (int ni = 0; ni < 4; ++ni) {
                int gcol = tile_n * 256 + wn * 64 + ni * 16 + cc;
                float v = acc[mi][ni][r] * scale;
                if (OM == 0)
                    ((u16*)Cout)[cb_off + grow * ldc + gcol] = f2h(v);
                else
                    ((float*)Cout)[cb_off + grow * ldc + gcol] = v;
            }
        }
    }
}

// ---------------------------------------------------------------------------
// single-pass causal softmax, T=1024: S fp32 [Z,T,T] -> P fp16 [Z,T,T]
// row in registers (4 floats/thread); zero-fill to round128(t+1) for PV.
// ---------------------------------------------------------------------------
__global__ __launch_bounds__(256) void softmax_causal(
    const float* __restrict__ S, u16* __restrict__ P)
{
    const int T = 1024;
    const int tq = blockIdx.x, z = blockIdx.y;
    const float* row = S + ((size_t)z * T + tq) * T;
    u16* prow = P + ((size_t)z * T + tq) * T;
    const int n = tq + 1;
    const int nw = ((tq >> 7) + 1) << 7;  // 128-rounded write limit
    const int tid = threadIdx.x;
    const int i0 = tid * 4;

    float4 v = ((const float4*)row)[tid];
    float e0 = (i0 + 0 < n) ? v.x : -1e30f;
    float e1 = (i0 + 1 < n) ? v.y : -1e30f;
    float e2 = (i0 + 2 < n) ? v.z : -1e30f;
    float e3 = (i0 + 3 < n) ? v.w : -1e30f;

    float m = fmaxf(fmaxf(e0, e1), fmaxf(e2, e3));
#pragma unroll
    for (int o = 1; o < 64; o <<= 1) m = fmaxf(m, __shfl_xor(m, o));
    __shared__ float red[4];
    if ((tid & 63) == 0) red[tid >> 6] = m;
    __syncthreads();
    m = fmaxf(fmaxf(red[0], red[1]), fmaxf(red[2], red[3]));

    float p0 = __expf(e0 - m), p1 = __expf(e1 - m);
    float p2 = __expf(e2 - m), p3 = __expf(e3 - m);
    float s = p0 + p1 + p2 + p3;
#pragma unroll
    for (int o = 1; o < 64; o <<= 1) s += __shfl_xor(s, o);
    __shared__ float red2[4];
    if ((tid & 63) == 0) red2[tid >> 6] = s;
    __syncthreads();
    const float inv = 1.0f / (red2[0] + red2[1] + red2[2] + red2[3]);

    if (i0 < nw) {
        ushort4 o4;
        o4.x = f2h(p0 * inv); o4.y = f2h(p1 * inv);
        o4.z = f2h(p2 * inv); o4.w = f2h(p3 * inv);
        ((ushort4*)prow)[tid] = o4;
    }
}

__global__ void cast_f32_f16(const float* __restrict__ src, u16* __restrict__ dst, int n4)
{
    int i = blockIdx.x * 256 + threadIdx.x;
    if (i < n4) {
        float4 v = ((const float4*)src)[i];
        ushort4 o;
        o.x = f2h(v.x); o.y = f2h(v.y); o.z = f2h(v.z); o.w = f2h(v.w);
        ((ushort4*)dst)[i] = o;
    }
}

extern "C" void kernel_launch(void* const* d_in, const int* in_sizes, int n_in,
                              void* d_out, int out_size, void* d_ws, size_t ws_size,
                              hipStream_t stream)
{
    (void)in_sizes; (void)n_in; (void)out_size; (void)ws_size;
    const int B = 4, T = 1024, C = 1024, H = 8;
    const int BT = B * T;   // 4096
    const int HC = H * C;   // 8192

    const float* data = (const float*)d_in[0];
    const float* Wq = (const float*)d_in[1];
    const float* Wk = (const float*)d_in[2];
    const float* Wv = (const float*)d_in[3];
    float* out = (float*)d_out;

    // workspace (440 MiB of the 512 MiB ws)
    char* p = (char*)d_ws;
    const size_t nData = (size_t)BT * C;      // 4M
    const size_t nW = (size_t)H * C * C;      // 8M
    const size_t nAll = (size_t)BT * HC;      // 32M
    const size_t nS = (size_t)B * H * T * T;  // 32M
    u16* dataH = (u16*)p; p += nData * 2;     //   8 MiB
    u16* WqH = (u16*)p; p += nW * 2;          //  16 MiB
    u16* WkH = (u16*)p; p += nW * 2;          //  16 MiB
    u16* WvH = (u16*)p; p += nW * 2;          //  16 MiB
    u16* Qa = (u16*)p; p += nAll * 2;         //  64 MiB
    u16* Ka = (u16*)p; p += nAll * 2;         //  64 MiB
    u16* VTa = (u16*)p; p += nAll * 2;        //  64 MiB
    float* S = (float*)p; p += nS * 4;        // 128 MiB
    u16* P = (u16*)p; p += nS * 2;            //  64 MiB

    const dim3 blk256(256), blk512(512);
    const float inv_sqrt_c = 1.0f / 32.0f;

    cast_f32_f16<<<dim3((unsigned)(nData / 4 / 256)), blk256, 0, stream>>>(data, dataH, (int)(nData / 4));
    cast_f32_f16<<<dim3((unsigned)(nW / 4 / 256)), blk256, 0, stream>>>(Wq, WqH, (int)(nW / 4));
    cast_f32_f16<<<dim3((unsigned)(nW / 4 / 256)), blk256, 0, stream>>>(Wk, WkH, (int)(nW / 4));
    cast_f32_f16<<<dim3((unsigned)(nW / 4 / 256)), blk256, 0, stream>>>(Wv, WvH, (int)(nW / 4));

    // Q/K projections: [4096,1024] x [8192,1024]^T -> fp16 [4096,8192]
    gemm_v3<0><<<dim3(HC / 256, BT / 128, 1), blk512, 0, stream>>>(
        dataH, WqH, Qa, C, C, HC, 0, 0, 0, 0, 0, 0, C, 1.0f);
    gemm_v3<0><<<dim3(HC / 256, BT / 128, 1), blk512, 0, stream>>>(
        dataH, WkH, Ka, C, C, HC, 0, 0, 0, 0, 0, 0, C, 1.0f);

    // V^T directly: VT[z][c][t] = sum_k Wv[h][c][k] data[b][t][k]
    gemm_v3<0><<<dim3(T / 256, C / 128, B * H), blk512, 0, stream>>>(
        WvH, dataH, VTa, C, C, T,
        0, (long)C * C,               // A (Wv): h-stride
        (long)T * C, 0,               // B (data): b-stride
        (long)8 * C * T, (long)C * T, // C (VT): z-major
        C, 1.0f);

    // scores = Q K^T / sqrt(C), causal tiles, fp32
    gemm_v3<2><<<dim3(T / 256, T / 128, B * H), blk512, 0, stream>>>(
        Qa, Ka, S,
        HC, HC, T,
        (long)T * HC, C,
        (long)T * HC, C,
        (long)8 * T * T, (long)T * T,
        C, inv_sqrt_c);

    softmax_causal<<<dim3(T, B * H), blk256, 0, stream>>>(S, P);

    // out[b,t,h*C+d] = sum_s P[t,s] VT[d,s], causal K-limit
    gemm_v3<3><<<dim3(C / 256, T / 128, B * H), blk512, 0, stream>>>(
        P, VTa, out,
        T, T, HC,
        (long)8 * T * T, (long)T * T,
        (long)8 * C * T, (long)C * T,
        (long)T * HC, C,
        T, 1.0f);
}

// Round 5
// 465.913 us; speedup vs baseline: 1.1779x; 1.1779x over previous
//
#include <hip/hip_runtime.h>
#include <hip/hip_fp16.h>

// ---------------------------------------------------------------------------
// Heads: per-head QKV projections + causal attention, B=4 T=1024 C=1024 H=8.
// Round 5: round-3 256x256 8-phase GEMM base, with (1) raw builtin barriers +
// clobber-free counted waitcnts (the m201 template's exact sync idiom; the
// round-3 "memory"-clobbered asm plausibly forced vmcnt(0) drains per phase),
// (2) PV round-pairing balance flip. Structure otherwise identical to round 3.
// ---------------------------------------------------------------------------

typedef unsigned short u16;
typedef _Float16 f16x8 __attribute__((ext_vector_type(8)));
typedef float f32x4 __attribute__((ext_vector_type(4)));

__device__ __forceinline__ u16 f2h(float f) {
    union { __half h; u16 u; } cv;
    cv.h = __float2half(f);
    return cv.u;
}

// global -> LDS direct copy, 16B/lane (wave-uniform LDS base + lane*16).
__device__ __forceinline__ void gload_lds16(const u16* g, const u16* lds_base, unsigned off_bytes) {
    unsigned a32 = (unsigned)(uintptr_t)((const char*)lds_base + off_bytes);
    a32 = __builtin_amdgcn_readfirstlane(a32);
    __builtin_amdgcn_global_load_lds(
        (const __attribute__((address_space(1))) void*)(uintptr_t)g,
        (__attribute__((address_space(3))) void*)a32,
        16, 0, 0);
}

// ---------------------------------------------------------------------------
// gemm256: D[m,n] = scale * sum_k A[m,k] * Bt[n,k]  (both operands [rows][K])
// 256x256 tile, BK=64, 512 threads = 8 waves (2M x 4N), per-wave 128x64 out.
// LDS: [dbuf 2][mat 2][khalf 2] x (256 rows x 32 cols fp16 = 16KB) = 128 KB.
// Swizzle (T2): byte ^= ((row>>1)&3)<<4  (2-way residual, free).
// OM: 0 = fp16 out, 2 = fp32 out + causal tile skip, 3 = fp32 + causal K-limit.
// z-batch: offsets (z>>3)*hi + (z&7)*lo.
// ---------------------------------------------------------------------------
template <int OM>
__global__ __launch_bounds__(512, 2) void gemm256(
    const u16* __restrict__ A, const u16* __restrict__ Bt, void* __restrict__ Cout,
    int lda, int ldb, int ldc,
    long sA_hi, long sA_lo, long sB_hi, long sB_lo, long sC_hi, long sC_lo,
    int K, float scale)
{
    const int tile_n = blockIdx.x, z = blockIdx.z;
    // PV balance: a CU's two resident blocks are id and id+256 (same x,y; z+16).
    // NT depends on tile_m only -> flip tile_m for the z>=16 half so a long
    // block pairs with a short one instead of its twin.
    const int tile_m = (OM == 3 && (z & 16)) ? (gridDim.y - 1 - blockIdx.y)
                                             : blockIdx.y;
    if (OM == 2 && tile_n > tile_m) return;  // causal: skip upper-tri tiles

    const int zh = z >> 3, zl = z & 7;
    const u16* Ab = A + (size_t)zh * sA_hi + (size_t)zl * sA_lo + (size_t)tile_m * 256 * lda;
    const u16* Bb = Bt + (size_t)zh * sB_hi + (size_t)zl * sB_lo + (size_t)tile_n * 256 * ldb;

    __shared__ u16 lds[8 * 8192];  // halfbase(db,mat,ks) = ((db<<2)|(mat<<1)|ks)*8192

    const int t = threadIdx.x, w = t >> 6, l = t & 63;
    const int wm = w >> 2, wn = w & 3;
    const int frow = l & 15, fch = l >> 4;

    const int Kend = (OM == 3) ? min(K, (tile_m + 1) * 256) : K;
    const int NT = Kend / 64;  // even, >= 4 at all call sites

    // staging constants: linear chunk clin -> logical (row, chunk) involution
    const int clin = w * 64 + l;
    const int srow = clin >> 2;
    const int sch = (clin & 3) ^ ((clin >> 3) & 3);
    const long eA = (long)srow * lda + sch * 8;
    const long eB = (long)srow * ldb + sch * 8;

    f32x4 acc[8][4] = {};
    f16x8 af[4], bf[4];

    // STAGE one K-half (16KB): mat 0=A 1=B, ks 0/1, tile tt, dbuf db
#define STAGE(DB, MAT, KS, TT) do {                                            \
        const u16* g_ = (MAT == 0 ? Ab + (size_t)(TT) * 64 + (KS) * 32 + eA    \
                                  : Bb + (size_t)(TT) * 64 + (KS) * 32 + eB);  \
        const u16* hb_ = lds + ((((DB) << 2) | ((MAT) << 1) | (KS)) << 13);    \
        gload_lds16(g_, hb_, (unsigned)(w * 64 * 16));                         \
        gload_lds16(g_ + (size_t)128 * (MAT == 0 ? lda : ldb), hb_,            \
                    (unsigned)((512 + w * 64) * 16));                          \
    } while (0)

    // swizzled fragment read
#define RD(DB, MAT, KS, ROW)                                                   \
    (*(const f16x8*)((const char*)(lds + ((((DB) << 2) | ((MAT) << 1) | (KS)) << 13)) + \
                     ((unsigned)((ROW) * 64 + fch * 16) ^ ((((ROW) >> 1) & 3) << 4))))

#define VM6 do { asm volatile("s_waitcnt vmcnt(6)"); \
                 __builtin_amdgcn_sched_barrier(0); } while (0)
#define VM0 do { asm volatile("s_waitcnt vmcnt(0)"); \
                 __builtin_amdgcn_sched_barrier(0); } while (0)
#define NOPW ((void)0)

    // one phase: ds-reads | prefetch | bar | lgkm | MFMA quad | wait | bar
#define PH(DB, KS, MH, WAITC, ...) do {                                        \
        if ((MH) == 0) {                                                       \
            _Pragma("unroll") for (int ni = 0; ni < 4; ++ni)                   \
                bf[ni] = RD(DB, 1, KS, wn * 64 + ni * 16 + frow);              \
        }                                                                      \
        _Pragma("unroll") for (int m4 = 0; m4 < 4; ++m4)                       \
            af[m4] = RD(DB, 0, KS, wm * 128 + ((MH) * 4 + m4) * 16 + frow);    \
        __VA_ARGS__;                                                           \
        __builtin_amdgcn_sched_barrier(0);                                     \
        __builtin_amdgcn_s_barrier();                                          \
        asm volatile("s_waitcnt lgkmcnt(0)");                                  \
        __builtin_amdgcn_sched_barrier(0);                                     \
        __builtin_amdgcn_s_setprio(1);                                         \
        _Pragma("unroll") for (int m4 = 0; m4 < 4; ++m4)                       \
            _Pragma("unroll") for (int ni = 0; ni < 4; ++ni)                   \
                acc[(MH) * 4 + m4][ni] = __builtin_amdgcn_mfma_f32_16x16x32_f16( \
                    af[m4], bf[ni], acc[(MH) * 4 + m4][ni], 0, 0, 0);          \
        __builtin_amdgcn_s_setprio(0);                                         \
        __builtin_amdgcn_sched_barrier(0);                                     \
        WAITC;                                                                 \
        __builtin_amdgcn_s_barrier();                                          \
    } while (0)

    // prologue: tile0 (4 halves) + tile1 (3 halves; A-ks1(1) issued at p0)
    STAGE(0, 1, 0, 0); STAGE(0, 0, 0, 0); STAGE(0, 1, 1, 0); STAGE(0, 0, 1, 0);
    STAGE(1, 1, 0, 1); STAGE(1, 0, 0, 1); STAGE(1, 1, 1, 1);
    VM6;  // tile0's 4 halves landed (last 3 halves = 6 loads outstanding)
    __builtin_amdgcn_s_barrier();

    for (int tt = 0; tt < NT; tt += 2) {
        const bool more = (tt + 2) < NT;  // NT even => tt+3 < NT iff tt+2 < NT
        PH(0, 0, 0, NOPW, STAGE(1, 0, 1, tt + 1));              // p0
        PH(0, 0, 1, NOPW, if (more) STAGE(0, 1, 0, tt + 2));    // p1
        PH(0, 1, 0, NOPW, if (more) STAGE(0, 0, 0, tt + 2));    // p2
        PH(0, 1, 1, if (more) VM6; else VM0,
                    if (more) STAGE(0, 1, 1, tt + 2));          // p3: tile t+1 ready
        PH(1, 0, 0, NOPW, if (more) STAGE(0, 0, 1, tt + 2));    // p4
        PH(1, 0, 1, NOPW, if (more) STAGE(1, 1, 0, tt + 3));    // p5
        PH(1, 1, 0, NOPW, if (more) STAGE(1, 0, 0, tt + 3));    // p6
        PH(1, 1, 1, if (more) VM6; else VM0,
                    if (more) STAGE(1, 1, 1, tt + 3));          // p7: tile t+2 ready
    }
#undef PH
#undef RD
#undef STAGE

    // epilogue: C/D layout col = l&15, row = (l>>4)*4 + r
    const int r0 = (l >> 4) * 4, cc = l & 15;
    const size_t cb_off = (size_t)zh * sC_hi + (size_t)zl * sC_lo;
#pragma unroll
    for (int mi = 0; mi < 8; ++mi) {
#pragma unroll
        for (int r = 0; r < 4; ++r) {
            size_t grow = (size_t)(tile_m * 256 + wm * 128 + mi * 16 + r0 + r);
#pragma unroll
            for (int ni = 0; ni < 4; ++ni) {
                int gcol = tile_n * 256 + wn * 64 + ni * 16 + cc;
                float v = acc[mi][ni][r] * scale;
                if (OM == 0)
                    ((u16*)Cout)[cb_off + grow * ldc + gcol] = f2h(v);
                else
                    ((float*)Cout)[cb_off + grow * ldc + gcol] = v;
            }
        }
    }
}

// ---------------------------------------------------------------------------
// single-pass causal softmax, T=1024: S fp32 [Z,T,T] -> P fp16 [Z,T,T]
// row in registers (4 floats/thread); zero-fill to round256(t+1) for PV.
// ---------------------------------------------------------------------------
__global__ __launch_bounds__(256) void softmax_causal(
    const float* __restrict__ S, u16* __restrict__ P)
{
    const int T = 1024;
    const int tq = blockIdx.x, z = blockIdx.y;
    const float* row = S + ((size_t)z * T + tq) * T;
    u16* prow = P + ((size_t)z * T + tq) * T;
    const int n = tq + 1;
    const int nw = ((tq >> 8) + 1) << 8;  // 256-rounded write limit
    const int tid = threadIdx.x;
    const int i0 = tid * 4;

    float4 v = ((const float4*)row)[tid];
    float e0 = (i0 + 0 < n) ? v.x : -1e30f;
    float e1 = (i0 + 1 < n) ? v.y : -1e30f;
    float e2 = (i0 + 2 < n) ? v.z : -1e30f;
    float e3 = (i0 + 3 < n) ? v.w : -1e30f;

    float m = fmaxf(fmaxf(e0, e1), fmaxf(e2, e3));
#pragma unroll
    for (int o = 1; o < 64; o <<= 1) m = fmaxf(m, __shfl_xor(m, o));
    __shared__ float red[4];
    if ((tid & 63) == 0) red[tid >> 6] = m;
    __syncthreads();
    m = fmaxf(fmaxf(red[0], red[1]), fmaxf(red[2], red[3]));

    float p0 = __expf(e0 - m), p1 = __expf(e1 - m);
    float p2 = __expf(e2 - m), p3 = __expf(e3 - m);
    float s = p0 + p1 + p2 + p3;
#pragma unroll
    for (int o = 1; o < 64; o <<= 1) s += __shfl_xor(s, o);
    __shared__ float red2[4];
    if ((tid & 63) == 0) red2[tid >> 6] = s;
    __syncthreads();
    const float inv = 1.0f / (red2[0] + red2[1] + red2[2] + red2[3]);

    if (i0 < nw) {
        ushort4 o4;
        o4.x = f2h(p0 * inv); o4.y = f2h(p1 * inv);
        o4.z = f2h(p2 * inv); o4.w = f2h(p3 * inv);
        ((ushort4*)prow)[tid] = o4;
    }
}

__global__ void cast_f32_f16(const float* __restrict__ src, u16* __restrict__ dst, int n4)
{
    int i = blockIdx.x * 256 + threadIdx.x;
    if (i < n4) {
        float4 v = ((const float4*)src)[i];
        ushort4 o;
        o.x = f2h(v.x); o.y = f2h(v.y); o.z = f2h(v.z); o.w = f2h(v.w);
        ((ushort4*)dst)[i] = o;
    }
}

extern "C" void kernel_launch(void* const* d_in, const int* in_sizes, int n_in,
                              void* d_out, int out_size, void* d_ws, size_t ws_size,
                              hipStream_t stream)
{
    (void)in_sizes; (void)n_in; (void)out_size; (void)ws_size;
    const int B = 4, T = 1024, C = 1024, H = 8;
    const int BT = B * T;   // 4096
    const int HC = H * C;   // 8192

    const float* data = (const float*)d_in[0];
    const float* Wq = (const float*)d_in[1];
    const float* Wk = (const float*)d_in[2];
    const float* Wv = (const float*)d_in[3];
    float* out = (float*)d_out;

    // workspace (440 MiB of the 512 MiB ws)
    char* p = (char*)d_ws;
    const size_t nData = (size_t)BT * C;      // 4M
    const size_t nW = (size_t)H * C * C;      // 8M
    const size_t nAll = (size_t)BT * HC;      // 32M
    const size_t nS = (size_t)B * H * T * T;  // 32M
    u16* dataH = (u16*)p; p += nData * 2;     //   8 MiB
    u16* WqH = (u16*)p; p += nW * 2;          //  16 MiB
    u16* WkH = (u16*)p; p += nW * 2;          //  16 MiB
    u16* WvH = (u16*)p; p += nW * 2;          //  16 MiB
    u16* Qa = (u16*)p; p += nAll * 2;         //  64 MiB
    u16* Ka = (u16*)p; p += nAll * 2;         //  64 MiB
    u16* VTa = (u16*)p; p += nAll * 2;        //  64 MiB
    float* S = (float*)p; p += nS * 4;        // 128 MiB
    u16* P = (u16*)p; p += nS * 2;            //  64 MiB

    const dim3 blk256(256), blk512(512);
    const float inv_sqrt_c = 1.0f / 32.0f;

    cast_f32_f16<<<dim3((unsigned)(nData / 4 / 256)), blk256, 0, stream>>>(data, dataH, (int)(nData / 4));
    cast_f32_f16<<<dim3((unsigned)(nW / 4 / 256)), blk256, 0, stream>>>(Wq, WqH, (int)(nW / 4));
    cast_f32_f16<<<dim3((unsigned)(nW / 4 / 256)), blk256, 0, stream>>>(Wk, WkH, (int)(nW / 4));
    cast_f32_f16<<<dim3((unsigned)(nW / 4 / 256)), blk256, 0, stream>>>(Wv, WvH, (int)(nW / 4));

    // Q/K projections: [4096,1024] x [8192,1024]^T -> fp16 [4096,8192]
    gemm256<0><<<dim3(HC / 256, BT / 256, 1), blk512, 0, stream>>>(
        dataH, WqH, Qa, C, C, HC, 0, 0, 0, 0, 0, 0, C, 1.0f);
    gemm256<0><<<dim3(HC / 256, BT / 256, 1), blk512, 0, stream>>>(
        dataH, WkH, Ka, C, C, HC, 0, 0, 0, 0, 0, 0, C, 1.0f);

    // V^T directly: VT[z][c][t] = sum_k Wv[h][c][k] data[b][t][k]
    gemm256<0><<<dim3(T / 256, C / 256, B * H), blk512, 0, stream>>>(
        WvH, dataH, VTa, C, C, T,
        0, (long)C * C,               // A (Wv): h-stride
        (long)T * C, 0,               // B (data): b-stride
        (long)8 * C * T, (long)C * T, // C (VT): z-major
        C, 1.0f);

    // scores = Q K^T / sqrt(C), causal tiles, fp32
    gemm256<2><<<dim3(T / 256, T / 256, B * H), blk512, 0, stream>>>(
        Qa, Ka, S,
        HC, HC, T,
        (long)T * HC, C,
        (long)T * HC, C,
        (long)8 * T * T, (long)T * T,
        C, inv_sqrt_c);

    softmax_causal<<<dim3(T, B * H), blk256, 0, stream>>>(S, P);

    // out[b,t,h*C+d] = sum_s P[t,s] VT[d,s], causal K-limit
    gemm256<3><<<dim3(C / 256, T / 256, B * H), blk512, 0, stream>>>(
        P, VTa, out,
        T, T, HC,
        (long)8 * T * T, (long)T * T,
        (long)8 * C * T, (long)C * T,
        (long)T * HC, C,
        T, 1.0f);
}